// Round 7
// baseline (2811.758 us; speedup 1.0000x reference)
//
#include <hip/hip_runtime.h>
#include <hip/hip_bf16.h>
#include <math.h>

#define NLAT_I 240
#define NLON_I 480
#define NLAT_O 361
#define NLON_O 720
#define CI_N 32
#define CO_N 32
#define K_N 7
#define WOFF 10
#define WLAT 21

#define PI_F 3.14159265358979323846f
#define TWOPI_F 6.28318530717958647692f
#define DLAT_V (PI_F / 360.0f)
#define DPHI_V (TWOPI_F / 720.0f)
#define CUTOFF_V (3.25f * PI_F / 120.0f)
#define DR_V (CUTOFF_V / 3.0f)
#define IDR_V (1.0f / DR_V)
#define DPH_V (TWOPI_F / 3.0f)
#define IDPH_V (1.0f / DPH_V)
#define QF_V (DLAT_V * DPHI_V)

#define PAD_T 64        // Toeplitz pad (covers fragment reach beyond support)
#define CT 64           // positions per work item
#define NBLK 512        // 2 blocks/CU (LDS ~76KB, 240 VGPR -> 2 waves/SIMD)
#define NC45 45         // 720/16 column chunks
#define NE 7581         // 361*21

typedef __attribute__((ext_vector_type(8))) short short8v;
typedef __attribute__((ext_vector_type(4))) short short4v;
typedef __attribute__((ext_vector_type(16))) float f32x16;

__device__ __forceinline__ unsigned short f2bf(float f) {
  __hip_bfloat16 h = __float2bfloat16(f);   // RTNE
  union { __hip_bfloat16 b; unsigned short s; } u; u.b = h; return u.s;
}

// async global->LDS DMA, 16B per lane; LDS dest is wave-uniform base + lane*16
typedef __attribute__((address_space(1))) const unsigned int ga_u32_t;
typedef __attribute__((address_space(3))) unsigned int ls_u32_t;
__device__ __forceinline__ void dma16(const unsigned short* g, unsigned short* l) {
  __builtin_amdgcn_global_load_lds((ga_u32_t*)(const void*)g,
                                   (ls_u32_t*)(void*)l, 16, 0, 0);
}

// ---------------- psi evaluation --------------------------------------------
__device__ __forceinline__ void psi_eval(float ct, float st, float cg, float sg,
                                         float q, float bang, float v[7]) {
  float sb, cb;
  sincosf(bang, &sb, &cb);
  float dx = sg * cb - st;
  float dy = sg * sb;
  float dz = cg - ct;
  float c2 = dx * dx + dy * dy + dz * dz;
  float r = 2.0f * asinf(fminf(1.0f, 0.5f * sqrtf(c2)));
  if (r <= CUTOFF_V) {
    float xx = ct * cb * sg - st * cg;
    float yy = sb * sg;
    float phi = atan2f(yy, xx);
    if (phi < 0.0f) phi += TWOPI_F;
    v[0] = fmaxf(0.0f, 1.0f - r * IDR_V) * q;
#pragma unroll
    for (int k = 1; k < 7; ++k) {
      const float irdr = (float)(1 + (k - 1) / 3) * DR_V;
      const float ipph = (float)((k - 1) % 3) * DPH_V;
      float rad = fmaxf(0.0f, 1.0f - fabsf(r - irdr) * IDR_V);
      float dd = fabsf(phi - ipph);
      dd = fminf(dd, TWOPI_F - dd);
      float az = fmaxf(0.0f, 1.0f - dd * IDPH_V);
      v[k] = rad * az * q;
    }
  } else {
#pragma unroll
    for (int k = 0; k < 7; ++k) v[k] = 0.0f;
  }
}

// per-(t,d) lon window half-width: -1 empty, 360 full circle
__device__ __forceinline__ int windowB(int t, int d) {
  int tp = t + d - WOFF;
  if (tp < 0 || tp > NLAT_O - 1) return -1;
  float th = (float)t * DLAT_V, ga = (float)tp * DLAT_V;
  float st = sinf(th), ct = cosf(th), sg = sinf(ga), cg = cosf(ga);
  float den = st * sg;
  float num = cosf(CUTOFF_V) - ct * cg;
  if (den < 1e-9f) return (fabsf(th - ga) <= CUTOFF_V) ? 360 : -1;
  if (num >= den) return -1;
  if (num <= -den) return 360;
  int B = (int)ceilf(acosf(num / den) * (1.0f / DPHI_V)) + 1;  // +1 margin; psi masks
  return B > 360 ? 360 : B;
}

__device__ __forceinline__ int nsupOf(int B) { return (B >= 360) ? 720 : 2 * B + 1; }
__device__ __forceinline__ int widthOf(int B) {
  return (B < 0) ? 0 : ((nsupOf(B) + 129) & ~1);   // even
}

// ---------------- kernel 0: prep (w2, scans, tables, counters) --------------
__global__ void prep_kernel(const float* __restrict__ w, unsigned short* __restrict__ w2,
                            int* __restrict__ offsF, int* __restrict__ offsT,
                            int* __restrict__ wtab, float* __restrict__ sums,
                            int* __restrict__ counter, int* __restrict__ gB,
                            int* __restrict__ gUc) {
  const int tid = threadIdx.x;
  __shared__ int temp[256];
  if (tid < 8) counter[tid] = 0;
  for (int idx = tid; idx < 361 * 7; idx += 256) sums[idx] = 0.0f;
  // w2[c16][o][kk] = bf16(w[o][i][k]) with ci=c16*16+kk, k=ci>>5, i=ci&31
  for (int idx = tid; idx < 14 * 32 * 16; idx += 256) {
    int kk = idx & 15; int o = (idx >> 4) & 31; int c16 = idx >> 9;
    int ci = c16 * 16 + kk; int i = ci & 31; int k = ci >> 5;
    w2[idx] = f2bf(w[(o * 32 + i) * 7 + k]);
  }
  for (int e = tid; e < NE; e += 256) {
    int t = e / 21, d = e % 21;
    int B = windowB(t, d);
    gB[e] = B;
    offsF[e] = (B >= 0) ? nsupOf(B) * 7 : 0;
    offsT[e] = 14 * widthOf(B);
  }
  __syncthreads();
  for (int t = tid; t < 361; t += 256) {
    int run = 0;
    for (int d = 0; d < WLAT; ++d) {
      gUc[t * 22 + d] = run;
      int B = gB[t * 21 + d];
      int np = (B >= 0) ? ((31 + B) >> 4) + ((B + 15) >> 4) + 1 : 0;
      run += np;
    }
    gUc[t * 22 + 21] = run;
    wtab[t] = run;
  }
  __syncthreads();
  // two-level exclusive scan for offsF then offsT (chunk = 30, 256*30 >= NE)
#pragma unroll 1
  for (int pass = 0; pass < 2; ++pass) {
    int* a = pass ? offsT : offsF;
    int s = tid * 30, e = s + 30; if (e > NE) e = NE; if (s > NE) s = NE;
    int sum = 0;
    for (int i = s; i < e; ++i) sum += a[i];
    temp[tid] = sum;
    __syncthreads();
    if (tid == 0) {
      int run = 0;
      for (int i = 0; i < 256; ++i) { int v = temp[i]; temp[i] = run; run += v; }
      a[NE] = run;
    }
    __syncthreads();
    int run = temp[tid];
    for (int i = s; i < e; ++i) { int v = a[i]; a[i] = run; run += v; }
    __syncthreads();
  }
}

// ---------------- kernel 1: bilinear upsample -> tiled bf16 XT --------------
// XT[t][c][i][kk] with b = c*16+kk  (wave A-load = contiguous 1KB)
__global__ void upsample_kernel(const float* __restrict__ x,
                                unsigned short* __restrict__ XT) {
  int idx = blockIdx.x * 256 + threadIdx.x;
  if (idx >= NLAT_O * NC45 * 512) return;
  int kk = idx & 15;
  int i = (idx >> 4) & 31;
  int c = (idx >> 9) % NC45;
  int t = idx / (NC45 * 512);
  int p = c * 16 + kk;

  double post = (double)t * (239.0 / 360.0);
  int i0 = (int)floor(post);
  if (i0 < 0) i0 = 0;
  if (i0 > NLAT_I - 1) i0 = NLAT_I - 1;
  int i1 = i0 + 1; if (i1 > NLAT_I - 1) i1 = NLAT_I - 1;
  float wt = (float)(post - (double)i0);

  double posp = (double)p * (2.0 / 3.0);
  double j0f = floor(posp);
  int j0 = ((int)j0f) % NLON_I;
  int j1 = (j0 + 1) % NLON_I;
  float wp = (float)(posp - j0f);

  const float* xi = x + (size_t)i * (NLAT_I * NLON_I);
  float a = xi[i0 * NLON_I + j0];
  float b = xi[i0 * NLON_I + j1];
  float cc = xi[i1 * NLON_I + j0];
  float d = xi[i1 * NLON_I + j1];
  float l0 = (1.0f - wt) * a + wt * cc;
  float l1 = (1.0f - wt) * b + wt * d;
  XT[idx] = f2bf((1.0f - wp) * l0 + wp * l1);
}

// ---------------- kernel 2: raw psi (f32) + fused per-(k,t) partial sums ----
__global__ void psi_raw_kernel(const int* __restrict__ offsF,
                               float* __restrict__ PSIF,
                               float* __restrict__ sums) {
  int t = blockIdx.x, d = blockIdx.y;
  int B = windowB(t, d);
  if (B < 0) return;
  int nsup = nsupOf(B);
  int bLo = (B >= 360) ? -360 : -B;
  int offF = offsF[t * 21 + d];
  int tp = t + d - WOFF;
  float th = (float)t * DLAT_V, ga = (float)tp * DLAT_V;
  float st, ct, sg, cg;
  sincosf(th, &st, &ct);
  sincosf(ga, &sg, &cg);
  float q = sg * QF_V;
  float acc[7];
#pragma unroll
  for (int k = 0; k < 7; ++k) acc[k] = 0.0f;
  for (int ix = threadIdx.x; ix < nsup; ix += 256) {
    float v[7];
    psi_eval(ct, st, cg, sg, q, (float)(bLo + ix) * DPHI_V, v);
#pragma unroll
    for (int k = 0; k < 7; ++k) { PSIF[offF + k * nsup + ix] = v[k]; acc[k] += v[k]; }
  }
#pragma unroll
  for (int k = 0; k < 7; ++k) {
    float a = acc[k];
    for (int off = 32; off > 0; off >>= 1) a += __shfl_down(a, off, 64);
    acc[k] = a;
  }
  __shared__ float red[4][7];
  int wid = threadIdx.x >> 6;
  if ((threadIdx.x & 63) == 0) {
#pragma unroll
    for (int k = 0; k < 7; ++k) red[wid][k] = acc[k];
  }
  __syncthreads();
  if (threadIdx.x == 0) {
#pragma unroll
    for (int k = 0; k < 7; ++k)
      atomicAdd(&sums[t * 7 + k], red[0][k] + red[1][k] + red[2][k] + red[3][k]);
  }
}

// ---------------- kernel 3: normalized bf16 Toeplitz (2 parity copies) ------
__global__ void psi_toep_kernel(const int* __restrict__ offsF,
                                const int* __restrict__ offsT,
                                const float* __restrict__ PSIF,
                                const float* __restrict__ sums,
                                unsigned short* __restrict__ PSIT) {
  int t = blockIdx.x, d = blockIdx.y;
  int B = windowB(t, d);
  if (B < 0) return;
  int nsup = nsupOf(B);
  int width = widthOf(B);
  int offF = offsF[t * 21 + d];
  int offT = offsT[t * 21 + d];
  float rc[7];
#pragma unroll
  for (int k = 0; k < 7; ++k) rc[k] = 1.0f / fmaxf(sums[t * 7 + k], 1e-8f);
  for (int ix = threadIdx.x; ix <= width; ix += 256) {
    int isup = ix - PAD_T;
    unsigned short vv[7];
    if (isup >= 0 && isup < nsup) {
#pragma unroll
      for (int k = 0; k < 7; ++k)
        vv[k] = f2bf(PSIF[offF + k * nsup + isup] * rc[k]);
    } else {
#pragma unroll
      for (int k = 0; k < 7; ++k) vv[k] = 0;
    }
    if (ix < width) {
#pragma unroll
      for (int k = 0; k < 7; ++k) PSIT[offT + (2 * k) * width + ix] = vv[k];
    }
    if (ix >= 1) {
#pragma unroll
      for (int k = 0; k < 7; ++k) PSIT[offT + (2 * k + 1) * width + ix - 1] = vv[k];
    }
  }
}

// ---------------- kernel 4: persistent MFMA conv, 2 blocks/CU DMA pipeline --
// Diagnosis (r5/r6): r5 at 1 wave/SIMD is SERIAL-ISSUE bound (385cy/phase =
// MFMA 112 + ds_read ~108 + VALU ~79 + waits); regs (240<=256) allow 2
// waves/SIMD but LDS (153KB) capped 1 block/CU. r6's A-direct failed (vmcnt
// coupling). Fix: r5 all-DMA structure with LDS shrunk to ~76KB -> 2 blocks/
// CU; co-resident blocks are barrier-independent, so one block's MFMA hides
// the other's ds_read/VALU/waits. B ring 6 slots, A ring 4 slots/wave, b2
// aliased onto A-ring (used only post-loop). vmcnt(8) = stage-ahead 3 x 4ops.

#define VMW8 asm volatile("s_waitcnt vmcnt(8)" ::: "memory");
#define BARR  __builtin_amdgcn_s_barrier();

#define STAGEU(IDX) {                                                       \
    int ix_ = (IDX); if (ix_ > nUm1) ix_ = nUm1;                            \
    int mx_ = __builtin_amdgcn_readlane(mxL, ix_);                          \
    int my_ = __builtin_amdgcn_readlane(myL, ix_);                          \
    int wdt_ = my_ & 4095;                                                  \
    int dd_ = (my_ >> 12) & 31;                                             \
    int cc_ = ((my_ >> 17) & 63) - 32;                                      \
    int sl_ = ix_ % 6;                                                      \
    int sa_ = ix_ & 3;                                                      \
    int jb_ = mx_ + lconst;                                                 \
    const unsigned short* bs_ = PSIT + jb_ + ((jb_ & 1) ? (wdt_ - 1) : 0);  \
    unsigned short* bd_ = Bring + sl_ * 3584;                               \
    int ks_ = 2 * wdt_;                                                     \
    dma16(bs_ + r0B * ks_, bd_ + (r0B << 9));                               \
    dma16(bs_ + r1B * ks_, bd_ + (r1B << 9));                               \
    int v45_ = pw16 + cc_;                                                  \
    if (v45_ < 0) v45_ += NC45;                                             \
    if (v45_ >= NC45) v45_ -= NC45;                                         \
    int v45b_ = v45_ + 2; if (v45b_ >= NC45) v45b_ -= NC45;                 \
    int tpd_ = t + dd_ - WOFF;                                              \
    unsigned short* ad_ = Aring + (((wv << 2) + sa_) << 10);                \
    dma16(XT + (((size_t)(tpd_ * NC45 + v45_)) << 9) + laneA, ad_);         \
    dma16(XT + (((size_t)(tpd_ * NC45 + v45b_)) << 9) + laneA, ad_ + 512); }

#define READF(S, IDX) {                                                     \
    int sl_ = (IDX) % 6;                                                    \
    int sa_ = (IDX) & 3;                                                    \
    const unsigned short* bb_ = Bring + sl_ * 3584 + (lane << 3);           \
    B##S##0 = *(const short8v*)(bb_);                                       \
    B##S##1 = *(const short8v*)(bb_ + 512);                                 \
    B##S##2 = *(const short8v*)(bb_ + 1024);                                \
    B##S##3 = *(const short8v*)(bb_ + 1536);                                \
    B##S##4 = *(const short8v*)(bb_ + 2048);                                \
    B##S##5 = *(const short8v*)(bb_ + 2560);                                \
    B##S##6 = *(const short8v*)(bb_ + 3072);                                \
    const unsigned short* aa_ = Aring + (((wv << 2) + sa_) << 10) + (lane << 3); \
    A##S##a = *(const short8v*)(aa_);                                       \
    A##S##b = *(const short8v*)(aa_ + 512); }

#define MFMA14(S) {                                                         \
    accA0 = __builtin_amdgcn_mfma_f32_32x32x16_bf16(A##S##a, B##S##0, accA0, 0, 0, 0); \
    accB0 = __builtin_amdgcn_mfma_f32_32x32x16_bf16(A##S##b, B##S##0, accB0, 0, 0, 0); \
    accA1 = __builtin_amdgcn_mfma_f32_32x32x16_bf16(A##S##a, B##S##1, accA1, 0, 0, 0); \
    accB1 = __builtin_amdgcn_mfma_f32_32x32x16_bf16(A##S##b, B##S##1, accB1, 0, 0, 0); \
    accA2 = __builtin_amdgcn_mfma_f32_32x32x16_bf16(A##S##a, B##S##2, accA2, 0, 0, 0); \
    accB2 = __builtin_amdgcn_mfma_f32_32x32x16_bf16(A##S##b, B##S##2, accB2, 0, 0, 0); \
    accA3 = __builtin_amdgcn_mfma_f32_32x32x16_bf16(A##S##a, B##S##3, accA3, 0, 0, 0); \
    accB3 = __builtin_amdgcn_mfma_f32_32x32x16_bf16(A##S##b, B##S##3, accB3, 0, 0, 0); \
    accA4 = __builtin_amdgcn_mfma_f32_32x32x16_bf16(A##S##a, B##S##4, accA4, 0, 0, 0); \
    accB4 = __builtin_amdgcn_mfma_f32_32x32x16_bf16(A##S##b, B##S##4, accB4, 0, 0, 0); \
    accA5 = __builtin_amdgcn_mfma_f32_32x32x16_bf16(A##S##a, B##S##5, accA5, 0, 0, 0); \
    accB5 = __builtin_amdgcn_mfma_f32_32x32x16_bf16(A##S##b, B##S##5, accB5, 0, 0, 0); \
    accA6 = __builtin_amdgcn_mfma_f32_32x32x16_bf16(A##S##a, B##S##6, accA6, 0, 0, 0); \
    accB6 = __builtin_amdgcn_mfma_f32_32x32x16_bf16(A##S##b, B##S##6, accB6, 0, 0, 0); }

// packed dump: half HB of ACC (regs 8*HB..8*HB+7) into b2 rows for k-basis KK
#define DUMP2(ACC, KK, HB) {                                              \
    short4v q_;                                                           \
    q_[0]=(short)f2bf(ACC[8*(HB)+0]); q_[1]=(short)f2bf(ACC[8*(HB)+1]);   \
    q_[2]=(short)f2bf(ACC[8*(HB)+2]); q_[3]=(short)f2bf(ACC[8*(HB)+3]);   \
    *(short4v*)(b2 + ((KK) << 9) + b0_) = q_;                             \
    q_[0]=(short)f2bf(ACC[8*(HB)+4]); q_[1]=(short)f2bf(ACC[8*(HB)+5]);   \
    q_[2]=(short)f2bf(ACC[8*(HB)+6]); q_[3]=(short)f2bf(ACC[8*(HB)+7]);   \
    *(short4v*)(b2 + ((KK) << 9) + b0_ + 8) = q_; }

// full GEMM2 + atomics for one ptile's 7-k accumulator set
#define GEMM2PT(AC0, AC1, AC2, AC3, AC4, AC5, AC6, PTILE) {               \
    f32x16 Dy;                                                            \
    _Pragma("unroll") for (int z = 0; z < 16; ++z) Dy[z] = 0.0f;          \
    DUMP2(AC0, 0, 0) DUMP2(AC1, 1, 0) DUMP2(AC2, 2, 0) DUMP2(AC3, 3, 0)  \
    DUMP2(AC4, 4, 0) DUMP2(AC5, 5, 0) DUMP2(AC6, 6, 0)                    \
    _Pragma("unroll") for (int k2 = 0; k2 < 7; ++k2) {                    \
      short8v A2 = *(const short8v*)(w2g + (((2 * k2 + 0) * 32 + nn) << 4) + g8); \
      short8v B2f = *(const short8v*)(b2 + (k2 << 9) + (nn << 4) + g8);   \
      Dy = __builtin_amdgcn_mfma_f32_32x32x16_bf16(A2, B2f, Dy, 0, 0, 0); \
    }                                                                     \
    DUMP2(AC0, 0, 1) DUMP2(AC1, 1, 1) DUMP2(AC2, 2, 1) DUMP2(AC3, 3, 1)  \
    DUMP2(AC4, 4, 1) DUMP2(AC5, 5, 1) DUMP2(AC6, 6, 1)                    \
    _Pragma("unroll") for (int k2 = 0; k2 < 7; ++k2) {                    \
      short8v A2 = *(const short8v*)(w2g + (((2 * k2 + 1) * 32 + nn) << 4) + g8); \
      short8v B2f = *(const short8v*)(b2 + (k2 << 9) + (nn << 4) + g8);   \
      Dy = __builtin_amdgcn_mfma_f32_32x32x16_bf16(A2, B2f, Dy, 0, 0, 0); \
    }                                                                     \
    const int p_ = (PTILE) * 32 + nn;                                     \
    if (p_ < NLON_O) {                                                    \
      _Pragma("unroll") for (int rr = 0; rr < 16; ++rr) {                 \
        int o = (rr & 3) + 8 * (rr >> 2) + 4 * g;                         \
        atomicAdd(&y[((size_t)o * NLAT_O + t) * NLON_O + p_], Dy[rr]);    \
      }                                                                   \
    } }

__global__ __launch_bounds__(256, 2) void disco_kernel(
    const unsigned short* __restrict__ XT, const unsigned short* __restrict__ PSIT,
    const unsigned short* __restrict__ w2g, const int* __restrict__ offsT,
    const int* __restrict__ wtab, const int* __restrict__ gB,
    const int* __restrict__ gUc, float* __restrict__ y,
    int* __restrict__ counter) {
  const int tid = threadIdx.x;
  __shared__ __align__(16) unsigned short Bring[6 * 3584];   // 42KB shared B ring
  __shared__ __align__(16) unsigned short Aring[4 * 4096];   // 32KB A ring; b2 alias
  __shared__ int Sbuf[362];
  __shared__ int sB[WLAT], sUc[WLAT + 1], sOff[WLAT], sW[WLAT];
  __shared__ int curItem, sSv;

  // ---- schedule (no trig: wtab precomputed); 3 pgroup-PAIRS per t-part ----
  for (int j = tid; j < 361; j += 256) {
    int t = (j & 1) ? 360 - (j >> 1) : (j >> 1);   // poles first
    Sbuf[j] = 3 * ((wtab[t] + CT - 1) / CT);
  }
  __syncthreads();
  if (tid == 0) {
    int run = 0;
    for (int j = 0; j < 361; ++j) { int v = Sbuf[j]; Sbuf[j] = run; run += v; }
    Sbuf[361] = run;
    sSv = 0;
  }
  __syncthreads();
  const int NTOT = Sbuf[361];
  const int xcd = blockIdx.x & 7;

  const int lane = tid & 63, wv = tid >> 6, nn = lane & 31, g = lane >> 5;
  const int g8 = g * 8;
  const int laneA = nn * 16 + g8;
  const int lconst = g8 - nn;
  const int r0B = (wv < 3) ? 2 * wv : 6;   // B-rows this wave stages
  const int r1B = (wv < 3) ? 2 * wv + 1 : 6;

  while (true) {
    // XCD-chunked dynamic scheduling: own chunk first, steal when exhausted.
    if (tid == 0) {
      int mm = NTOT;
      int s2 = sSv;
      while (s2 < 8) {
        int cx = (xcd + s2) & 7;
        int b0 = (NTOT * cx) >> 3;
        int b1 = (NTOT * (cx + 1)) >> 3;
        int off = atomicAdd(&counter[cx], 1);
        if (b0 + off < b1) { mm = b0 + off; break; }
        ++s2;
      }
      sSv = s2;
      curItem = mm;
    }
    __syncthreads();   // full barrier: also drains vmcnt (stale DMA safety)
    const int m = curItem;
    if (m >= NTOT) break;

    int lo = 0, hi = 360;
    while (lo < hi) {
      int mid = (lo + hi + 1) >> 1;
      if (Sbuf[mid] <= m) lo = mid; else hi = mid - 1;
    }
    const int j = lo;
    const int r = m - Sbuf[j];
    const int t = (j & 1) ? 360 - (j >> 1) : (j >> 1);
    const int pgpair = r % 3;
    const int part = r / 3;

    if (tid < WLAT) {
      int B = gB[t * 21 + tid];
      sB[tid] = B;
      sOff[tid] = offsT[t * 21 + tid];
      sW[tid] = widthOf(B);
    }
    if (tid < WLAT + 1) sUc[tid] = gUc[t * 22 + tid];
    __syncthreads();

    const int Wt = sUc[WLAT];
    int g0 = part * CT, g1 = g0 + CT;
    if (g1 > Wt) g1 = Wt;
    const int nU = g1 - g0;
    const int nUm1 = nU - 1;

    const int ptileA = pgpair * 8 + 2 * wv;   // even ptile; pair = +1 (0..23)
    const int pw16 = ptileA * 2;

    // ---- per-lane unit metadata (lane u holds unit u; readlane at stage) ----
    int mxL, myL;
    {
      int uu_ = lane; if (uu_ > nUm1) uu_ = nUm1;
      int ug_ = g0 + uu_;
      int dd = 0;
      while (dd < 20 && sUc[dd + 1] <= ug_) ++dd;
      int Bv = sB[dd];
      int bLo_ = (Bv >= 360) ? -360 : -Bv;
      int cc_ = -((Bv + 15) >> 4) + (ug_ - sUc[dd]);
      mxL = sOff[dd] + cc_ * 16 - bLo_ + PAD_T;
      myL = sW[dd] | (dd << 12) | ((cc_ + 32) << 17);
    }

    f32x16 accA0, accA1, accA2, accA3, accA4, accA5, accA6;
    f32x16 accB0, accB1, accB2, accB3, accB4, accB5, accB6;
#pragma unroll
    for (int z = 0; z < 16; ++z) {
      accA0[z]=0; accA1[z]=0; accA2[z]=0; accA3[z]=0; accA4[z]=0; accA5[z]=0; accA6[z]=0;
      accB0[z]=0; accB1[z]=0; accB2[z]=0; accB3[z]=0; accB4[z]=0; accB5[z]=0; accB6[z]=0;
    }

    short8v AXa, AXb, BX0, BX1, BX2, BX3, BX4, BX5, BX6;
    short8v AYa, AYb, BY0, BY1, BY2, BY3, BY4, BY5, BY6;

    // ---- prologue: fill ring 3 deep, sync, read unit 0 ----
    STAGEU(0) STAGEU(1) STAGEU(2)
    VMW8 BARR
    READF(X, 0)

    // ---- flat unit loop, 2-unit consume pipeline, per-unit barrier ----
    int u = 0;
    while (true) {
      STAGEU(u + 3)
      VMW8 BARR
      int nx = u + 1; bool h1 = (nx < nU); if (!h1) nx = u;
      READF(Y, nx)
      MFMA14(X)
      if (!h1) break;
      STAGEU(u + 4)
      VMW8 BARR
      int nx2 = u + 2; bool h2 = (nx2 < nU); if (!h2) nx2 = nx;
      READF(X, nx2)
      MFMA14(Y)
      if (!h2) break;
      u += 2;
    }

    // ---- GEMM2 for both ptiles (b2 aliased onto this wave's A-ring) ----
    unsigned short* b2 = Aring + (wv << 12);
    const int b0_ = nn * 16 + 4 * g;
    GEMM2PT(accA0, accA1, accA2, accA3, accA4, accA5, accA6, ptileA)
    GEMM2PT(accB0, accB1, accB2, accB3, accB4, accB5, accB6, ptileA + 1)
  }
}

// ---------------- launch ----------------------------------------------------
extern "C" void kernel_launch(void* const* d_in, const int* in_sizes, int n_in,
                              void* d_out, int out_size, void* d_ws, size_t ws_size,
                              hipStream_t stream) {
  (void)in_sizes; (void)n_in; (void)out_size; (void)ws_size;
  const float* x = (const float*)d_in[0];
  const float* w = (const float*)d_in[1];
  float* y = (float*)d_out;

  // ws: XT (16.6MB) | PSIF f32 (24MB cap) | PSIT bf16 (52MB cap) | small tables
  unsigned short* XT = (unsigned short*)d_ws;                 // 8,317,440 shorts
  float* PSIF = (float*)(XT + (size_t)NLAT_O * NC45 * 512);   // cap 6e6 f32
  unsigned short* PSIT = (unsigned short*)(PSIF + 6000000);   // cap 26e6 shorts
  unsigned short* w2 = PSIT + 26000000;                       // 7168
  float* sums = (float*)(w2 + 7168);                          // 2527
  int* offsF = (int*)(sums + NLAT_O * K_N);                   // NE+1
  int* offsT = offsF + NE + 1;                                // NE+1
  int* wtab = offsT + NE + 1;                                 // 361
  int* counter = wtab + 361;                                  // 8
  int* gB = counter + 8;                                      // NE
  int* gUc = gB + NE;                                         // 361*22

  hipMemsetAsync(y, 0, (size_t)CO_N * NLAT_O * NLON_O * sizeof(float), stream);

  prep_kernel<<<1, 256, 0, stream>>>(w, w2, offsF, offsT, wtab, sums, counter, gB, gUc);
  int n_up = NLAT_O * NC45 * 512;
  upsample_kernel<<<(n_up + 255) / 256, 256, 0, stream>>>(x, XT);
  psi_raw_kernel<<<dim3(NLAT_O, WLAT), 256, 0, stream>>>(offsF, PSIF, sums);
  psi_toep_kernel<<<dim3(NLAT_O, WLAT), 256, 0, stream>>>(offsF, offsT, PSIF, sums, PSIT);
  disco_kernel<<<NBLK, 256, 0, stream>>>(XT, PSIT, w2, offsT, wtab, gB, gUc, y, counter);
}

// Round 8
// 477.953 us; speedup vs baseline: 5.8829x; 5.8829x over previous
//
#include <hip/hip_runtime.h>
#include <hip/hip_bf16.h>
#include <math.h>

#define NLAT_I 240
#define NLON_I 480
#define NLAT_O 361
#define NLON_O 720
#define CI_N 32
#define CO_N 32
#define K_N 7
#define WOFF 10
#define WLAT 21

#define PI_F 3.14159265358979323846f
#define TWOPI_F 6.28318530717958647692f
#define DLAT_V (PI_F / 360.0f)
#define DPHI_V (TWOPI_F / 720.0f)
#define CUTOFF_V (3.25f * PI_F / 120.0f)
#define DR_V (CUTOFF_V / 3.0f)
#define IDR_V (1.0f / DR_V)
#define DPH_V (TWOPI_F / 3.0f)
#define IDPH_V (1.0f / DPH_V)
#define QF_V (DLAT_V * DPHI_V)

#define PAD_T 64        // Toeplitz pad (covers fragment reach beyond support)
#define CT 128          // positions per work item (big items amortize overhead)
#define NBLK 256        // 1 block/CU (LDS ~148KB, ~245 VGPR -> 1 wave/SIMD)
#define NC45 45         // 720/16 column chunks
#define NE 7581         // 361*21

typedef __attribute__((ext_vector_type(8))) short short8v;
typedef __attribute__((ext_vector_type(4))) short short4v;
typedef __attribute__((ext_vector_type(16))) float f32x16;

__device__ __forceinline__ unsigned short f2bf(float f) {
  __hip_bfloat16 h = __float2bfloat16(f);   // RTNE
  union { __hip_bfloat16 b; unsigned short s; } u; u.b = h; return u.s;
}

// async global->LDS DMA, 16B per lane; LDS dest is wave-uniform base + lane*16
typedef __attribute__((address_space(1))) const unsigned int ga_u32_t;
typedef __attribute__((address_space(3))) unsigned int ls_u32_t;
__device__ __forceinline__ void dma16(const unsigned short* g, unsigned short* l) {
  __builtin_amdgcn_global_load_lds((ga_u32_t*)(const void*)g,
                                   (ls_u32_t*)(void*)l, 16, 0, 0);
}

// ---------------- psi evaluation --------------------------------------------
__device__ __forceinline__ void psi_eval(float ct, float st, float cg, float sg,
                                         float q, float bang, float v[7]) {
  float sb, cb;
  sincosf(bang, &sb, &cb);
  float dx = sg * cb - st;
  float dy = sg * sb;
  float dz = cg - ct;
  float c2 = dx * dx + dy * dy + dz * dz;
  float r = 2.0f * asinf(fminf(1.0f, 0.5f * sqrtf(c2)));
  if (r <= CUTOFF_V) {
    float xx = ct * cb * sg - st * cg;
    float yy = sb * sg;
    float phi = atan2f(yy, xx);
    if (phi < 0.0f) phi += TWOPI_F;
    v[0] = fmaxf(0.0f, 1.0f - r * IDR_V) * q;
#pragma unroll
    for (int k = 1; k < 7; ++k) {
      const float irdr = (float)(1 + (k - 1) / 3) * DR_V;
      const float ipph = (float)((k - 1) % 3) * DPH_V;
      float rad = fmaxf(0.0f, 1.0f - fabsf(r - irdr) * IDR_V);
      float dd = fabsf(phi - ipph);
      dd = fminf(dd, TWOPI_F - dd);
      float az = fmaxf(0.0f, 1.0f - dd * IDPH_V);
      v[k] = rad * az * q;
    }
  } else {
#pragma unroll
    for (int k = 0; k < 7; ++k) v[k] = 0.0f;
  }
}

// per-(t,d) lon window half-width: -1 empty, 360 full circle
__device__ __forceinline__ int windowB(int t, int d) {
  int tp = t + d - WOFF;
  if (tp < 0 || tp > NLAT_O - 1) return -1;
  float th = (float)t * DLAT_V, ga = (float)tp * DLAT_V;
  float st = sinf(th), ct = cosf(th), sg = sinf(ga), cg = cosf(ga);
  float den = st * sg;
  float num = cosf(CUTOFF_V) - ct * cg;
  if (den < 1e-9f) return (fabsf(th - ga) <= CUTOFF_V) ? 360 : -1;
  if (num >= den) return -1;
  if (num <= -den) return 360;
  int B = (int)ceilf(acosf(num / den) * (1.0f / DPHI_V)) + 1;  // +1 margin; psi masks
  return B > 360 ? 360 : B;
}

__device__ __forceinline__ int nsupOf(int B) { return (B >= 360) ? 720 : 2 * B + 1; }
__device__ __forceinline__ int widthOf(int B) {
  return (B < 0) ? 0 : ((nsupOf(B) + 129) & ~1);   // even
}

// ---------------- kernel 0: prep (w2, scans, tables, counters) --------------
// w2 kk-slots are PERMUTED: slot kk holds i_local = 4*(kk>>3)+(kk&3)+8*((kk>>2)&1)
// to match the single-b128 acc dump layout (see DUMP2).
__global__ void prep_kernel(const float* __restrict__ w, unsigned short* __restrict__ w2,
                            int* __restrict__ offsF, int* __restrict__ offsT,
                            int* __restrict__ wtab, float* __restrict__ sums,
                            int* __restrict__ counter, int* __restrict__ gB,
                            int* __restrict__ gUc) {
  const int tid = threadIdx.x;
  __shared__ int temp[256];
  if (tid < 8) counter[tid] = 0;
  for (int idx = tid; idx < 361 * 7; idx += 256) sums[idx] = 0.0f;
  for (int idx = tid; idx < 14 * 32 * 16; idx += 256) {
    int kk = idx & 15; int o = (idx >> 4) & 31; int c16 = idx >> 9;
    int il = 4 * (kk >> 3) + (kk & 3) + 8 * ((kk >> 2) & 1);   // perm(kk)
    int i = (c16 & 1) * 16 + il; int k = c16 >> 1;
    w2[idx] = f2bf(w[(o * 32 + i) * 7 + k]);
  }
  for (int e = tid; e < NE; e += 256) {
    int t = e / 21, d = e % 21;
    int B = windowB(t, d);
    gB[e] = B;
    offsF[e] = (B >= 0) ? nsupOf(B) * 7 : 0;
    offsT[e] = 14 * widthOf(B);
  }
  __syncthreads();
  for (int t = tid; t < 361; t += 256) {
    int run = 0;
    for (int d = 0; d < WLAT; ++d) {
      gUc[t * 22 + d] = run;
      int B = gB[t * 21 + d];
      int np = (B >= 0) ? ((31 + B) >> 4) + ((B + 15) >> 4) + 1 : 0;
      run += np;
    }
    gUc[t * 22 + 21] = run;
    wtab[t] = run;
  }
  __syncthreads();
  // two-level exclusive scan for offsF then offsT (chunk = 30, 256*30 >= NE)
#pragma unroll 1
  for (int pass = 0; pass < 2; ++pass) {
    int* a = pass ? offsT : offsF;
    int s = tid * 30, e = s + 30; if (e > NE) e = NE; if (s > NE) s = NE;
    int sum = 0;
    for (int i = s; i < e; ++i) sum += a[i];
    temp[tid] = sum;
    __syncthreads();
    if (tid == 0) {
      int run = 0;
      for (int i = 0; i < 256; ++i) { int v = temp[i]; temp[i] = run; run += v; }
      a[NE] = run;
    }
    __syncthreads();
    int run = temp[tid];
    for (int i = s; i < e; ++i) { int v = a[i]; a[i] = run; run += v; }
    __syncthreads();
  }
}

// ---------------- kernel 1: bilinear upsample -> tiled bf16 XT --------------
// XT[t][c][i][kk] with b = c*16+kk  (wave A-load = contiguous 1KB)
__global__ void upsample_kernel(const float* __restrict__ x,
                                unsigned short* __restrict__ XT) {
  int idx = blockIdx.x * 256 + threadIdx.x;
  if (idx >= NLAT_O * NC45 * 512) return;
  int kk = idx & 15;
  int i = (idx >> 4) & 31;
  int c = (idx >> 9) % NC45;
  int t = idx / (NC45 * 512);
  int p = c * 16 + kk;

  double post = (double)t * (239.0 / 360.0);
  int i0 = (int)floor(post);
  if (i0 < 0) i0 = 0;
  if (i0 > NLAT_I - 1) i0 = NLAT_I - 1;
  int i1 = i0 + 1; if (i1 > NLAT_I - 1) i1 = NLAT_I - 1;
  float wt = (float)(post - (double)i0);

  double posp = (double)p * (2.0 / 3.0);
  double j0f = floor(posp);
  int j0 = ((int)j0f) % NLON_I;
  int j1 = (j0 + 1) % NLON_I;
  float wp = (float)(posp - j0f);

  const float* xi = x + (size_t)i * (NLAT_I * NLON_I);
  float a = xi[i0 * NLON_I + j0];
  float b = xi[i0 * NLON_I + j1];
  float cc = xi[i1 * NLON_I + j0];
  float d = xi[i1 * NLON_I + j1];
  float l0 = (1.0f - wt) * a + wt * cc;
  float l1 = (1.0f - wt) * b + wt * d;
  XT[idx] = f2bf((1.0f - wp) * l0 + wp * l1);
}

// ---------------- kernel 2: raw psi (f32) + fused per-(k,t) partial sums ----
__global__ void psi_raw_kernel(const int* __restrict__ offsF,
                               float* __restrict__ PSIF,
                               float* __restrict__ sums) {
  int t = blockIdx.x, d = blockIdx.y;
  int B = windowB(t, d);
  if (B < 0) return;
  int nsup = nsupOf(B);
  int bLo = (B >= 360) ? -360 : -B;
  int offF = offsF[t * 21 + d];
  int tp = t + d - WOFF;
  float th = (float)t * DLAT_V, ga = (float)tp * DLAT_V;
  float st, ct, sg, cg;
  sincosf(th, &st, &ct);
  sincosf(ga, &sg, &cg);
  float q = sg * QF_V;
  float acc[7];
#pragma unroll
  for (int k = 0; k < 7; ++k) acc[k] = 0.0f;
  for (int ix = threadIdx.x; ix < nsup; ix += 256) {
    float v[7];
    psi_eval(ct, st, cg, sg, q, (float)(bLo + ix) * DPHI_V, v);
#pragma unroll
    for (int k = 0; k < 7; ++k) { PSIF[offF + k * nsup + ix] = v[k]; acc[k] += v[k]; }
  }
#pragma unroll
  for (int k = 0; k < 7; ++k) {
    float a = acc[k];
    for (int off = 32; off > 0; off >>= 1) a += __shfl_down(a, off, 64);
    acc[k] = a;
  }
  __shared__ float red[4][7];
  int wid = threadIdx.x >> 6;
  if ((threadIdx.x & 63) == 0) {
#pragma unroll
    for (int k = 0; k < 7; ++k) red[wid][k] = acc[k];
  }
  __syncthreads();
  if (threadIdx.x == 0) {
#pragma unroll
    for (int k = 0; k < 7; ++k)
      atomicAdd(&sums[t * 7 + k], red[0][k] + red[1][k] + red[2][k] + red[3][k]);
  }
}

// ---------------- kernel 3: normalized bf16 Toeplitz (2 parity copies) ------
__global__ void psi_toep_kernel(const int* __restrict__ offsF,
                                const int* __restrict__ offsT,
                                const float* __restrict__ PSIF,
                                const float* __restrict__ sums,
                                unsigned short* __restrict__ PSIT) {
  int t = blockIdx.x, d = blockIdx.y;
  int B = windowB(t, d);
  if (B < 0) return;
  int nsup = nsupOf(B);
  int width = widthOf(B);
  int offF = offsF[t * 21 + d];
  int offT = offsT[t * 21 + d];
  float rc[7];
#pragma unroll
  for (int k = 0; k < 7; ++k) rc[k] = 1.0f / fmaxf(sums[t * 7 + k], 1e-8f);
  for (int ix = threadIdx.x; ix <= width; ix += 256) {
    int isup = ix - PAD_T;
    unsigned short vv[7];
    if (isup >= 0 && isup < nsup) {
#pragma unroll
      for (int k = 0; k < 7; ++k)
        vv[k] = f2bf(PSIF[offF + k * nsup + isup] * rc[k]);
    } else {
#pragma unroll
      for (int k = 0; k < 7; ++k) vv[k] = 0;
    }
    if (ix < width) {
#pragma unroll
      for (int k = 0; k < 7; ++k) PSIT[offT + (2 * k) * width + ix] = vv[k];
    }
    if (ix >= 1) {
#pragma unroll
      for (int k = 0; k < 7; ++k) PSIT[offT + (2 * k + 1) * width + ix - 1] = vv[k];
    }
  }
}

// ---------------- kernel 4: persistent MFMA conv (r5 + halved sync) ---------
// r5 (357us) was the best structure: dual-ptile acc (224 regs, 1 wave/SIMD is
// register-forced: r7's 2-waves attempt spilled catastrophically). Remaining
// overhead terms attacked here: (1) ONE vmcnt+barrier per TWO units (was per
// unit); (2) CT=128 halves per-item overhead (sched/prologue/GEMM2); (3) acc
// dump = single ds_write_b128 via i-permuted G layout (w2 permuted to match).

#define VMW8 asm volatile("s_waitcnt vmcnt(8)" ::: "memory");
#define BARR  __builtin_amdgcn_s_barrier();

#define GETMETA(IX) \
    int mx_, my_; \
    if ((IX) & 64) { mx_ = __builtin_amdgcn_readlane(mxL1, (IX) & 63); \
                     my_ = __builtin_amdgcn_readlane(myL1, (IX) & 63); } \
    else           { mx_ = __builtin_amdgcn_readlane(mxL0, (IX) & 63); \
                     my_ = __builtin_amdgcn_readlane(myL0, (IX) & 63); }

#define STAGEU(IDX) {                                                       \
    int ix_ = (IDX); if (ix_ > nUm1) ix_ = nUm1;                            \
    GETMETA(ix_)                                                            \
    int wdt_ = my_ & 4095;                                                  \
    int dd_ = (my_ >> 12) & 31;                                             \
    int cc_ = ((my_ >> 17) & 63) - 32;                                      \
    int sl_ = ix_ & 7;                                                      \
    int jb_ = mx_ + lconst;                                                 \
    const unsigned short* bs_ = PSIT + jb_ + ((jb_ & 1) ? (wdt_ - 1) : 0);  \
    unsigned short* bd_ = Bring + sl_ * 3584;                               \
    int ks_ = 2 * wdt_;                                                     \
    dma16(bs_ + r0B * ks_, bd_ + (r0B << 9));                               \
    dma16(bs_ + r1B * ks_, bd_ + (r1B << 9));                               \
    int v45_ = pw16 + cc_;                                                  \
    if (v45_ < 0) v45_ += NC45;                                             \
    if (v45_ >= NC45) v45_ -= NC45;                                         \
    int v45b_ = v45_ + 2; if (v45b_ >= NC45) v45b_ -= NC45;                 \
    int tpd_ = t + dd_ - WOFF;                                              \
    unsigned short* ad_ = Aring + (((wv << 3) + sl_) << 10);                \
    dma16(XT + (((size_t)(tpd_ * NC45 + v45_)) << 9) + laneA, ad_);         \
    dma16(XT + (((size_t)(tpd_ * NC45 + v45b_)) << 9) + laneA, ad_ + 512); }

#define READF(S, IDX) {                                                     \
    int sl_ = (IDX) & 7;                                                    \
    const unsigned short* bb_ = Bring + sl_ * 3584 + (lane << 3);           \
    B##S##0 = *(const short8v*)(bb_);                                       \
    B##S##1 = *(const short8v*)(bb_ + 512);                                 \
    B##S##2 = *(const short8v*)(bb_ + 1024);                                \
    B##S##3 = *(const short8v*)(bb_ + 1536);                                \
    B##S##4 = *(const short8v*)(bb_ + 2048);                                \
    B##S##5 = *(const short8v*)(bb_ + 2560);                                \
    B##S##6 = *(const short8v*)(bb_ + 3072);                                \
    const unsigned short* aa_ = Aring + (((wv << 3) + sl_) << 10) + (lane << 3); \
    A##S##a = *(const short8v*)(aa_);                                       \
    A##S##b = *(const short8v*)(aa_ + 512); }

#define MFMA14(S) {                                                         \
    accA0 = __builtin_amdgcn_mfma_f32_32x32x16_bf16(A##S##a, B##S##0, accA0, 0, 0, 0); \
    accB0 = __builtin_amdgcn_mfma_f32_32x32x16_bf16(A##S##b, B##S##0, accB0, 0, 0, 0); \
    accA1 = __builtin_amdgcn_mfma_f32_32x32x16_bf16(A##S##a, B##S##1, accA1, 0, 0, 0); \
    accB1 = __builtin_amdgcn_mfma_f32_32x32x16_bf16(A##S##b, B##S##1, accB1, 0, 0, 0); \
    accA2 = __builtin_amdgcn_mfma_f32_32x32x16_bf16(A##S##a, B##S##2, accA2, 0, 0, 0); \
    accB2 = __builtin_amdgcn_mfma_f32_32x32x16_bf16(A##S##b, B##S##2, accB2, 0, 0, 0); \
    accA3 = __builtin_amdgcn_mfma_f32_32x32x16_bf16(A##S##a, B##S##3, accA3, 0, 0, 0); \
    accB3 = __builtin_amdgcn_mfma_f32_32x32x16_bf16(A##S##b, B##S##3, accB3, 0, 0, 0); \
    accA4 = __builtin_amdgcn_mfma_f32_32x32x16_bf16(A##S##a, B##S##4, accA4, 0, 0, 0); \
    accB4 = __builtin_amdgcn_mfma_f32_32x32x16_bf16(A##S##b, B##S##4, accB4, 0, 0, 0); \
    accA5 = __builtin_amdgcn_mfma_f32_32x32x16_bf16(A##S##a, B##S##5, accA5, 0, 0, 0); \
    accB5 = __builtin_amdgcn_mfma_f32_32x32x16_bf16(A##S##b, B##S##5, accB5, 0, 0, 0); \
    accA6 = __builtin_amdgcn_mfma_f32_32x32x16_bf16(A##S##a, B##S##6, accA6, 0, 0, 0); \
    accB6 = __builtin_amdgcn_mfma_f32_32x32x16_bf16(A##S##b, B##S##6, accB6, 0, 0, 0); }

// dump half HB of ACC (regs 8*HB..8*HB+7) as ONE b128 write; slot order matches
// w2's kk-permutation (prep): slot s holds i_local = 4*(s>>3)+(s&3)+8*((s>>2)&1)
#define DUMP2(ACC, KK, HB) {                                              \
    short8v q_;                                                           \
    q_[0]=(short)f2bf(ACC[8*(HB)+0]); q_[1]=(short)f2bf(ACC[8*(HB)+1]);   \
    q_[2]=(short)f2bf(ACC[8*(HB)+2]); q_[3]=(short)f2bf(ACC[8*(HB)+3]);   \
    q_[4]=(short)f2bf(ACC[8*(HB)+4]); q_[5]=(short)f2bf(ACC[8*(HB)+5]);   \
    q_[6]=(short)f2bf(ACC[8*(HB)+6]); q_[7]=(short)f2bf(ACC[8*(HB)+7]);   \
    *(short8v*)(b2 + ((KK) << 9) + b0_) = q_; }

// full GEMM2 + atomics for one ptile's 7-k accumulator set
#define GEMM2PT(AC0, AC1, AC2, AC3, AC4, AC5, AC6, PTILE) {               \
    f32x16 Dy;                                                            \
    _Pragma("unroll") for (int z = 0; z < 16; ++z) Dy[z] = 0.0f;          \
    DUMP2(AC0, 0, 0) DUMP2(AC1, 1, 0) DUMP2(AC2, 2, 0) DUMP2(AC3, 3, 0)  \
    DUMP2(AC4, 4, 0) DUMP2(AC5, 5, 0) DUMP2(AC6, 6, 0)                    \
    _Pragma("unroll") for (int k2 = 0; k2 < 7; ++k2) {                    \
      short8v A2 = *(const short8v*)(w2g + (((2 * k2 + 0) * 32 + nn) << 4) + g8); \
      short8v B2f = *(const short8v*)(b2 + (k2 << 9) + (nn << 4) + g8);   \
      Dy = __builtin_amdgcn_mfma_f32_32x32x16_bf16(A2, B2f, Dy, 0, 0, 0); \
    }                                                                     \
    DUMP2(AC0, 0, 1) DUMP2(AC1, 1, 1) DUMP2(AC2, 2, 1) DUMP2(AC3, 3, 1)  \
    DUMP2(AC4, 4, 1) DUMP2(AC5, 5, 1) DUMP2(AC6, 6, 1)                    \
    _Pragma("unroll") for (int k2 = 0; k2 < 7; ++k2) {                    \
      short8v A2 = *(const short8v*)(w2g + (((2 * k2 + 1) * 32 + nn) << 4) + g8); \
      short8v B2f = *(const short8v*)(b2 + (k2 << 9) + (nn << 4) + g8);   \
      Dy = __builtin_amdgcn_mfma_f32_32x32x16_bf16(A2, B2f, Dy, 0, 0, 0); \
    }                                                                     \
    const int p_ = (PTILE) * 32 + nn;                                     \
    if (p_ < NLON_O) {                                                    \
      _Pragma("unroll") for (int rr = 0; rr < 16; ++rr) {                 \
        int o = (rr & 3) + 8 * (rr >> 2) + 4 * g;                         \
        atomicAdd(&y[((size_t)o * NLAT_O + t) * NLON_O + p_], Dy[rr]);    \
      }                                                                   \
    } }

__global__ __launch_bounds__(256, 1) void disco_kernel(
    const unsigned short* __restrict__ XT, const unsigned short* __restrict__ PSIT,
    const unsigned short* __restrict__ w2g, const int* __restrict__ offsT,
    const int* __restrict__ wtab, const int* __restrict__ gB,
    const int* __restrict__ gUc, float* __restrict__ y,
    int* __restrict__ counter) {
  const int tid = threadIdx.x;
  __shared__ __align__(16) unsigned short Bring[8 * 3584];   // 56KB shared B ring
  __shared__ __align__(16) unsigned short Aring[32 * 1024];  // 64KB per-wave A ring
  __shared__ __align__(16) unsigned short b2all[4 * 3584];   // 28KB GEMM2 staging
  __shared__ int Sbuf[362];
  __shared__ int sB[WLAT], sUc[WLAT + 1], sOff[WLAT], sW[WLAT];
  __shared__ int curItem, sSv;

  // ---- schedule; 3 pgroup-PAIRS per t-part, CT=128 units per part ----
  for (int j = tid; j < 361; j += 256) {
    int t = (j & 1) ? 360 - (j >> 1) : (j >> 1);   // poles first
    Sbuf[j] = 3 * ((wtab[t] + CT - 1) / CT);
  }
  __syncthreads();
  if (tid == 0) {
    int run = 0;
    for (int j = 0; j < 361; ++j) { int v = Sbuf[j]; Sbuf[j] = run; run += v; }
    Sbuf[361] = run;
    sSv = 0;
  }
  __syncthreads();
  const int NTOT = Sbuf[361];
  const int xcd = blockIdx.x & 7;

  const int lane = tid & 63, wv = tid >> 6, nn = lane & 31, g = lane >> 5;
  const int g8 = g * 8;
  const int laneA = nn * 16 + g8;
  const int lconst = g8 - nn;
  const int r0B = (wv < 3) ? 2 * wv : 6;   // B-rows this wave stages
  const int r1B = (wv < 3) ? 2 * wv + 1 : 6;

  while (true) {
    // XCD-chunked dynamic scheduling: own chunk first, steal when exhausted.
    if (tid == 0) {
      int mm = NTOT;
      int s2 = sSv;
      while (s2 < 8) {
        int cx = (xcd + s2) & 7;
        int b0 = (NTOT * cx) >> 3;
        int b1 = (NTOT * (cx + 1)) >> 3;
        int off = atomicAdd(&counter[cx], 1);
        if (b0 + off < b1) { mm = b0 + off; break; }
        ++s2;
      }
      sSv = s2;
      curItem = mm;
    }
    __syncthreads();   // full barrier: also drains vmcnt (stale DMA safety)
    const int m = curItem;
    if (m >= NTOT) break;

    int lo = 0, hi = 360;
    while (lo < hi) {
      int mid = (lo + hi + 1) >> 1;
      if (Sbuf[mid] <= m) lo = mid; else hi = mid - 1;
    }
    const int j = lo;
    const int r = m - Sbuf[j];
    const int t = (j & 1) ? 360 - (j >> 1) : (j >> 1);
    const int pgpair = r % 3;
    const int part = r / 3;

    if (tid < WLAT) {
      int B = gB[t * 21 + tid];
      sB[tid] = B;
      sOff[tid] = offsT[t * 21 + tid];
      sW[tid] = widthOf(B);
    }
    if (tid < WLAT + 1) sUc[tid] = gUc[t * 22 + tid];
    __syncthreads();

    const int Wt = sUc[WLAT];
    int g0 = part * CT, g1 = g0 + CT;
    if (g1 > Wt) g1 = Wt;
    const int nU = g1 - g0;
    const int nUm1 = nU - 1;

    const int ptileA = pgpair * 8 + 2 * wv;   // even ptile; pair = +1 (0..23)
    const int pw16 = ptileA * 2;

    // ---- per-lane unit metadata: lane u holds units u and u+64 ----
    int mxL0, myL0, mxL1, myL1;
#pragma unroll
    for (int hfu = 0; hfu < 2; ++hfu) {
      int uu_ = lane + hfu * 64; if (uu_ > nUm1) uu_ = nUm1;
      int ug_ = g0 + uu_;
      int dd = 0;
      while (dd < 20 && sUc[dd + 1] <= ug_) ++dd;
      int Bv = sB[dd];
      int bLo_ = (Bv >= 360) ? -360 : -Bv;
      int cc_ = -((Bv + 15) >> 4) + (ug_ - sUc[dd]);
      int mxv = sOff[dd] + cc_ * 16 - bLo_ + PAD_T;
      int myv = sW[dd] | (dd << 12) | ((cc_ + 32) << 17);
      if (hfu == 0) { mxL0 = mxv; myL0 = myv; } else { mxL1 = mxv; myL1 = myv; }
    }

    f32x16 accA0, accA1, accA2, accA3, accA4, accA5, accA6;
    f32x16 accB0, accB1, accB2, accB3, accB4, accB5, accB6;
#pragma unroll
    for (int z = 0; z < 16; ++z) {
      accA0[z]=0; accA1[z]=0; accA2[z]=0; accA3[z]=0; accA4[z]=0; accA5[z]=0; accA6[z]=0;
      accB0[z]=0; accB1[z]=0; accB2[z]=0; accB3[z]=0; accB4[z]=0; accB5[z]=0; accB6[z]=0;
    }

    short8v AXa, AXb, BX0, BX1, BX2, BX3, BX4, BX5, BX6;
    short8v AYa, AYb, BY0, BY1, BY2, BY3, BY4, BY5, BY6;

    // ---- prologue: fill ring 4 deep, vmcnt(8) forces units 0,1 landed ----
    STAGEU(0) STAGEU(1) STAGEU(2) STAGEU(3)
    VMW8 BARR
    READF(X, 0)

    // ---- flat unit loop: TWO units per vmcnt+barrier ----
    int u = 0;
    while (true) {
      STAGEU(u + 4) STAGEU(u + 5)
      VMW8 BARR                        // forces u+2,u+3 landed (8 newest kept)
      int nx = u + 1; bool h1 = (nx < nU); if (!h1) nx = u;
      READF(Y, nx)
      MFMA14(X)
      if (!h1) break;
      int nx2 = u + 2; bool h2 = (nx2 < nU); if (!h2) nx2 = nx;
      READF(X, nx2)
      MFMA14(Y)
      if (!h2) break;
      u += 2;
    }

    // ---- GEMM2 for both ptiles (wave-private b2 buffer) ----
    unsigned short* b2 = b2all + wv * 3584;
    const int b0_ = nn * 16 + g8;
    GEMM2PT(accA0, accA1, accA2, accA3, accA4, accA5, accA6, ptileA)
    GEMM2PT(accB0, accB1, accB2, accB3, accB4, accB5, accB6, ptileA + 1)
  }
}

// ---------------- launch ----------------------------------------------------
extern "C" void kernel_launch(void* const* d_in, const int* in_sizes, int n_in,
                              void* d_out, int out_size, void* d_ws, size_t ws_size,
                              hipStream_t stream) {
  (void)in_sizes; (void)n_in; (void)out_size; (void)ws_size;
  const float* x = (const float*)d_in[0];
  const float* w = (const float*)d_in[1];
  float* y = (float*)d_out;

  // ws: XT (16.6MB) | PSIF f32 (24MB cap) | PSIT bf16 (52MB cap) | small tables
  unsigned short* XT = (unsigned short*)d_ws;                 // 8,317,440 shorts
  float* PSIF = (float*)(XT + (size_t)NLAT_O * NC45 * 512);   // cap 6e6 f32
  unsigned short* PSIT = (unsigned short*)(PSIF + 6000000);   // cap 26e6 shorts
  unsigned short* w2 = PSIT + 26000000;                       // 7168
  float* sums = (float*)(w2 + 7168);                          // 2527
  int* offsF = (int*)(sums + NLAT_O * K_N);                   // NE+1
  int* offsT = offsF + NE + 1;                                // NE+1
  int* wtab = offsT + NE + 1;                                 // 361
  int* counter = wtab + 361;                                  // 8
  int* gB = counter + 8;                                      // NE
  int* gUc = gB + NE;                                         // 361*22

  hipMemsetAsync(y, 0, (size_t)CO_N * NLAT_O * NLON_O * sizeof(float), stream);

  prep_kernel<<<1, 256, 0, stream>>>(w, w2, offsF, offsT, wtab, sums, counter, gB, gUc);
  int n_up = NLAT_O * NC45 * 512;
  upsample_kernel<<<(n_up + 255) / 256, 256, 0, stream>>>(x, XT);
  psi_raw_kernel<<<dim3(NLAT_O, WLAT), 256, 0, stream>>>(offsF, PSIF, sums);
  psi_toep_kernel<<<dim3(NLAT_O, WLAT), 256, 0, stream>>>(offsF, offsT, PSIF, sums, PSIT);
  disco_kernel<<<NBLK, 256, 0, stream>>>(XT, PSIT, w2, offsT, wtab, gB, gUc, y, counter);
}